// Round 10
// baseline (720.187 us; speedup 1.0000x reference)
//
#include <hip/hip_runtime.h>
#include <hip/hip_bf16.h>
#include <math.h>

#define R_CNT   20000
#define L_CNT   30
#define D_CNT   200
#define A_CNT   32
#define B_CNT   4096
#define NNZ_CNT 65536
#define AVG_RATING 3.8f

#define FLASH_GRID 5000   // 4 waves/block, one review per wave
#define TAIL_GRID  5000   // 4 reviews per block

// ---- d_out layout (floats) ----
#define OUT_OBJ  0
#define OUT_RL   1
#define OUT_AB   (1 + B_CNT)               // 4097
#define OUT_PRED (OUT_AB + 2*R_CNT)        // 44097
#define OUT_UA   (OUT_PRED + B_CNT)        // 48193
#define OUT_IA   (OUT_UA + B_CNT*A_CNT)    // 179265

// ---- ws layout (bytes) ----
#define WS_DBL    0         // double[4] (reserved)
#define WS_MODE   32        // int (1 => indices are int64 in memory)
#define WS_FMLIN  64        // float[4096]
#define WS_PT     16448     // float[R*32]
#define WS_V      2576448   // float[R*200]; k_flash overwrites row r with z_s
#define WS_JPART  18627648  // double[TAIL_GRID]
#define WS_SPART  18667648  // double[512]
#define WS_UPART  18671744  // float[32]

// Block-wide reduction of 4 channels across 256 threads (4 waves of 64).
__device__ __forceinline__ float4 blk_reduce4(float4 v, float4* scratch) {
    __syncthreads();
    #pragma unroll
    for (int o = 32; o >= 1; o >>= 1) {
        v.x += __shfl_xor(v.x, o);
        v.y += __shfl_xor(v.y, o);
        v.z += __shfl_xor(v.z, o);
        v.w += __shfl_xor(v.w, o);
    }
    int w = threadIdx.x >> 6;
    if ((threadIdx.x & 63) == 0) scratch[w] = v;
    __syncthreads();
    float4 t0 = scratch[0], t1 = scratch[1], t2 = scratch[2], t3 = scratch[3];
    return make_float4(t0.x + t1.x + t2.x + t3.x,
                       t0.y + t1.y + t2.y + t3.y,
                       t0.z + t1.z + t2.z + t3.z,
                       t0.w + t1.w + t2.w + t3.w);
}

// ---- K_pre: role-split fusion of {vgemm | uloss | init} ----
// blocks [0,313): V = y_s @ M_w (64 rows each)
// blocks [313,345): uloss G-row per block
// blocks [345,473): zero UA/IA; block 345 inits dbl/mode
__global__ __launch_bounds__(256) void k_pre(const float* __restrict__ y_s,
                                             const float* __restrict__ M_w,
                                             const float* __restrict__ T_w,
                                             const int* __restrict__ u_idx,
                                             float* __restrict__ V,
                                             float* __restrict__ upart,
                                             float* __restrict__ out,
                                             double* __restrict__ dbl,
                                             int* __restrict__ mode) {
    __shared__ __align__(16) float sh[8224];
    const int tid = threadIdx.x;
    const int bid = blockIdx.x;

    if (bid < 313) {
        float* Msh = sh;             // [25][260]
        float* Ysh = sh + 6500;      // [25][68]
        int r0 = bid * 64;
        int dg = tid & 31, rg = tid >> 5;
        float acc[8][8];
        #pragma unroll
        for (int i = 0; i < 8; i++)
            #pragma unroll
            for (int j = 0; j < 8; j++) acc[i][j] = 0.f;
        for (int e0 = 0; e0 < D_CNT; e0 += 25) {
            __syncthreads();
            for (int idx = tid; idx < 25 * 256; idx += 256) {
                int ee = idx >> 8, d = idx & 255;
                Msh[ee * 260 + d] = (d < D_CNT) ? M_w[(e0 + ee) * D_CNT + d] : 0.f;
            }
            for (int idx = tid; idx < 25 * 64; idx += 256) {
                int rr = idx / 25, ee = idx - rr * 25;
                int row = r0 + rr;
                Ysh[ee * 68 + rr] = (row < R_CNT) ? y_s[row * D_CNT + e0 + ee] : 0.f;
            }
            __syncthreads();
            for (int ee = 0; ee < 25; ee++) {
                const float4 ya = *(const float4*)&Ysh[ee * 68 + rg * 8];
                const float4 yb = *(const float4*)&Ysh[ee * 68 + rg * 8 + 4];
                const float4 ma = *(const float4*)&Msh[ee * 260 + dg * 8];
                const float4 mb = *(const float4*)&Msh[ee * 260 + dg * 8 + 4];
                float ys[8] = {ya.x, ya.y, ya.z, ya.w, yb.x, yb.y, yb.z, yb.w};
                float ms[8] = {ma.x, ma.y, ma.z, ma.w, mb.x, mb.y, mb.z, mb.w};
                #pragma unroll
                for (int i = 0; i < 8; i++)
                    #pragma unroll
                    for (int j = 0; j < 8; j++)
                        acc[i][j] = fmaf(ys[i], ms[j], acc[i][j]);
            }
        }
        if (dg < 25) {
            #pragma unroll
            for (int i = 0; i < 8; i++) {
                int row = r0 + rg * 8 + i;
                if (row < R_CNT) {
                    *(float4*)&V[row * D_CNT + dg * 8]     = make_float4(acc[i][0], acc[i][1], acc[i][2], acc[i][3]);
                    *(float4*)&V[row * D_CNT + dg * 8 + 4] = make_float4(acc[i][4], acc[i][5], acc[i][6], acc[i][7]);
                }
            }
        }
    } else if (bid < 345) {
        float* Tsh = sh;                         // 6400 floats
        float* tn  = sh + 6400;                  // 32
        float4* red4 = (float4*)(sh + 6448);     // 16 floats
        for (int idx = tid; idx < 1600; idx += 256)
            ((float4*)Tsh)[idx] = ((const float4*)T_w)[idx];
        __syncthreads();
        int a = tid >> 3, k = tid & 7;
        float p = 0.f;
        #pragma unroll
        for (int j = 0; j < 25; ++j) { float t = Tsh[(k + 8*j)*32 + a]; p = fmaf(t, t, p); }
        p += __shfl_xor(p, 1); p += __shfl_xor(p, 2); p += __shfl_xor(p, 4);
        if (k == 0) tn[a] = fmaxf(sqrtf(p), 1e-12f);
        __syncthreads();
        const int i = bid - 313;
        float s = 0.f;
        #pragma unroll
        for (int j = 0; j < 25; ++j)
            s = fmaf(Tsh[(k + 8*j)*32 + i], Tsh[(k + 8*j)*32 + a], s);
        s += __shfl_xor(s, 1); s += __shfl_xor(s, 2); s += __shfl_xor(s, 4);
        float part = 0.f;
        if (k == 0) {
            float g = s / (tn[i] * tn[a]);
            float diff = g - ((i == a) ? 1.f : 0.f);
            part = diff * diff;
        }
        float4 tot = blk_reduce4(make_float4(part, 0.f, 0.f, 0.f), red4);
        if (tid == 0) upart[i] = tot.x;
    } else {
        int base = (bid - 345) * 2048;
        #pragma unroll
        for (int j = 0; j < 8; ++j)
            out[OUT_UA + base + j * 256 + tid] = 0.f;
        if (bid == 345 && tid == 0) {
            dbl[0] = 0.0; dbl[1] = 0.0; dbl[2] = 0.0;
            int m = 1;
            for (int i = 1; i < 256; i += 2) if (u_idx[i] != 0) { m = 0; break; }
            *mode = m;
        }
    }
}

// ---- K_flash: wave-per-review online-softmax z_s. No LDS, no barriers. ----
// Lane j<50 owns d-slice [4j..4j+3]. e_w streamed once into registers;
// z_s written in place over V[r] (row dead after its own dx pass).
__global__ __launch_bounds__(256, 6) void k_flash(const float* __restrict__ e_w,
                                                  float* __restrict__ V) {
    const int lane = threadIdx.x & 63;
    const int r = blockIdx.x * 4 + (threadIdx.x >> 6);
    const bool act = lane < 50;
    const int dl = act ? lane : 0;

    const float4* ew4 = (const float4*)(e_w + (size_t)r * (L_CNT * D_CNT));
    float4 v4 = ((const float4*)(V + (size_t)r * D_CNT))[dl];

    float m = -3.0e38f, s = 0.f;
    float4 zs = make_float4(0.f, 0.f, 0.f, 0.f);
    float4 e0 = ew4[dl];
    float4 e1 = ew4[50 + dl];
    #pragma unroll
    for (int l = 0; l < L_CNT; l += 2) {
        float4 n0 = e0, n1 = e1;
        if (l + 2 < L_CNT) {
            n0 = ew4[(l + 2) * 50 + dl];
            n1 = ew4[(l + 3) * 50 + dl];
        }
        float p0 = act ? (e0.x*v4.x + e0.y*v4.y + e0.z*v4.z + e0.w*v4.w) : 0.f;
        float p1 = act ? (e1.x*v4.x + e1.y*v4.y + e1.z*v4.z + e1.w*v4.w) : 0.f;
        #pragma unroll
        for (int o = 1; o < 64; o <<= 1) {
            p0 += __shfl_xor(p0, o);
            p1 += __shfl_xor(p1, o);
        }
        float nm = fmaxf(m, fmaxf(p0, p1));
        float sc = __expf(m - nm);
        float w0 = __expf(p0 - nm);
        float w1 = __expf(p1 - nm);
        s = s * sc + w0 + w1;
        zs.x = zs.x * sc + w0 * e0.x + w1 * e1.x;
        zs.y = zs.y * sc + w0 * e0.y + w1 * e1.y;
        zs.z = zs.z * sc + w0 * e0.z + w1 * e1.z;
        zs.w = zs.w * sc + w0 * e0.w + w1 * e1.w;
        m = nm;
        e0 = n0; e1 = n1;
    }
    const float inv = 1.f / s;
    zs.x *= inv; zs.y *= inv; zs.z *= inv; zs.w *= inv;
    if (act) ((float4*)(V + (size_t)r * D_CNT))[lane] = zs;
}

// ---- K_tail: p_t + r_s + cosine hinge losses, 4 reviews per block ----
// W_w read once per block for 4 reviews (4 accumulators); T_w float4s read
// once for 4 reviews. Tiny LDS (~1.3KB) -> high occupancy.
__global__ __launch_bounds__(256) void k_tail(const float* __restrict__ zs,
                                              const float* __restrict__ z_n,
                                              const float* __restrict__ W_w,
                                              const float* __restrict__ W_b,
                                              const float* __restrict__ T_w,
                                              const float* __restrict__ T_b,
                                              float* __restrict__ p_t,
                                              float* __restrict__ out,
                                              double* __restrict__ jpart) {
    __shared__ __align__(16) float zsh[4 * D_CNT];
    __shared__ float pts[4 * 32];
    __shared__ float4 red[8];
    const int tid = threadIdx.x;
    const int w = tid >> 6;
    const int r0 = blockIdx.x * 4;

    for (int i = tid; i < 200; i += 256)   // 4 rows = 200 float4
        ((float4*)zsh)[i] = ((const float4*)(zs + (size_t)r0 * D_CNT))[i];

    float zn[8];
    #pragma unroll
    for (int q = 0; q < 8; ++q) zn[q] = 0.f;
    if (tid < D_CNT) {
        #pragma unroll
        for (int q = 0; q < 4; ++q) {
            zn[2*q]   = z_n[(size_t)(2*(r0+q))     * D_CNT + tid];
            zn[2*q+1] = z_n[(size_t)(2*(r0+q) + 1) * D_CNT + tid];
        }
    }
    __syncthreads();

    {   // p_t for 4 reviews sharing each W_w load
        int a = tid >> 3, k = tid & 7;
        float a0 = 0.f, a1 = 0.f, a2 = 0.f, a3 = 0.f;
        #pragma unroll
        for (int j = 0; j < 25; ++j) {
            float wv = W_w[a * D_CNT + k + 8 * j];
            a0 = fmaf(zsh[0*D_CNT + k + 8*j], wv, a0);
            a1 = fmaf(zsh[1*D_CNT + k + 8*j], wv, a1);
            a2 = fmaf(zsh[2*D_CNT + k + 8*j], wv, a2);
            a3 = fmaf(zsh[3*D_CNT + k + 8*j], wv, a3);
        }
        #pragma unroll
        for (int o = 1; o < 8; o <<= 1) {
            a0 += __shfl_xor(a0, o); a1 += __shfl_xor(a1, o);
            a2 += __shfl_xor(a2, o); a3 += __shfl_xor(a3, o);
        }
        if (k == 0) {
            float wbv = W_b[a];
            float p0 = a0 + wbv, p1 = a1 + wbv, p2 = a2 + wbv, p3 = a3 + wbv;
            pts[0*32+a] = p0; pts[1*32+a] = p1; pts[2*32+a] = p2; pts[3*32+a] = p3;
            p_t[(size_t)(r0+0) * 32 + a] = p0;
            p_t[(size_t)(r0+1) * 32 + a] = p1;
            p_t[(size_t)(r0+2) * 32 + a] = p2;
            p_t[(size_t)(r0+3) * 32 + a] = p3;
        }
    }
    __syncthreads();

    // r_s for 4 reviews sharing each T_w float4
    float rv[4] = {0.f, 0.f, 0.f, 0.f};
    float zv[4] = {0.f, 0.f, 0.f, 0.f};
    if (tid < D_CNT) {
        float tbv = T_b[tid];
        rv[0] = tbv; rv[1] = tbv; rv[2] = tbv; rv[3] = tbv;
        const float4* tw = (const float4*)(T_w + tid * 32);
        #pragma unroll
        for (int u = 0; u < 8; ++u) {
            float4 t = tw[u];
            #pragma unroll
            for (int q = 0; q < 4; ++q) {
                rv[q] = fmaf(t.x, pts[q*32 + 4*u + 0], rv[q]);
                rv[q] = fmaf(t.y, pts[q*32 + 4*u + 1], rv[q]);
                rv[q] = fmaf(t.z, pts[q*32 + 4*u + 2], rv[q]);
                rv[q] = fmaf(t.w, pts[q*32 + 4*u + 3], rv[q]);
            }
        }
        #pragma unroll
        for (int q = 0; q < 4; ++q) zv[q] = zsh[q * D_CNT + tid];
    }

    double jloc = 0.0;
    #pragma unroll
    for (int q = 0; q < 4; ++q) {
        float4 Av = make_float4(rv[q]*rv[q], rv[q]*zv[q], zv[q]*zv[q], zn[2*q]*zn[2*q]);
        float4 Bv = make_float4(zn[2*q]*rv[q], zn[2*q+1]*zn[2*q+1], zn[2*q+1]*rv[q], 0.f);
        #pragma unroll
        for (int o = 32; o >= 1; o >>= 1) {
            Av.x += __shfl_xor(Av.x, o); Av.y += __shfl_xor(Av.y, o);
            Av.z += __shfl_xor(Av.z, o); Av.w += __shfl_xor(Av.w, o);
            Bv.x += __shfl_xor(Bv.x, o); Bv.y += __shfl_xor(Bv.y, o);
            Bv.z += __shfl_xor(Bv.z, o);
        }
        if ((tid & 63) == 0) { red[2*w] = Av; red[2*w+1] = Bv; }
        __syncthreads();
        if (tid == 0) {
            float rr = 0.f, rz = 0.f, zz = 0.f, n00 = 0.f, n0r = 0.f, n11 = 0.f, n1r = 0.f;
            #pragma unroll
            for (int i = 0; i < 4; ++i) {
                float4 a = red[2*i], b = red[2*i+1];
                rr += a.x; rz += a.y; zz += a.z; n00 += a.w;
                n0r += b.x; n11 += b.y; n1r += b.z;
            }
            float nr = fmaxf(sqrtf(rr), 1e-12f);
            float nz = fmaxf(sqrtf(zz), 1e-12f);
            float c1  = rz  / (nr * nz);
            float c20 = n0r / (fmaxf(sqrtf(n00), 1e-12f) * nr);
            float c21 = n1r / (fmaxf(sqrtf(n11), 1e-12f) * nr);
            float l0 = fmaxf(0.f, 1.f - (c1 - c20));
            float l1 = fmaxf(0.f, 1.f - (c1 - c21));
            out[OUT_AB + 2 * (r0 + q)]     = l0;
            out[OUT_AB + 2 * (r0 + q) + 1] = l1;
            jloc += (double)l0 + (double)l1;
        }
        __syncthreads();
    }
    if (tid == 0) jpart[blockIdx.x] = jloc;
}

// ---- K_scatter: user/item aspect segment sums via atomics ----
__global__ __launch_bounds__(256) void k_scatter(const int* __restrict__ u_idx,
                                                 const int* __restrict__ i_idx,
                                                 const float* __restrict__ u_val,
                                                 const float* __restrict__ i_val,
                                                 const float* __restrict__ p_t,
                                                 const int* __restrict__ mode,
                                                 float* __restrict__ out) {
    long long gid = (long long)blockIdx.x * 256 + threadIdx.x;
    const long long HALF = (long long)NNZ_CNT * 32;
    int is_item = gid >= HALF;
    long long rem = gid - (is_item ? HALF : 0);
    int k = (int)(rem >> 5), a = (int)(rem & 31);
    const int* idx = is_item ? i_idx : u_idx;
    const float* val = is_item ? i_val : u_val;
    int m64 = *mode;
    int row, col;
    if (m64) { row = idx[2 * k]; col = idx[2 * (NNZ_CNT + k)]; }
    else     { row = idx[k];     col = idx[NNZ_CNT + k]; }
    float v = p_t[col * 32 + a] * val[k];
    float* base = out + (is_item ? OUT_IA : OUT_UA);
    atomicAdd(&base[row * 32 + a], v);
}

// ---- K_fm: FM per-b terms; per-block partial of the global scalar S ----
__global__ __launch_bounds__(256) void k_fm(const float* __restrict__ out,
                                            const float* __restrict__ fc_w,
                                            const float* __restrict__ fc_b,
                                            const float* __restrict__ fm_V,
                                            float* __restrict__ fm_lin,
                                            double* __restrict__ spart) {
    __shared__ float parts[8];
    int tid = threadIdx.x;
    int a = tid & 31;
    int b = blockIdx.x * 8 + (tid >> 5);
    float ua = out[OUT_UA + b * 32 + a];
    float ia = out[OUT_IA + b * 32 + a];
    float oe = ua * ia;
    float oe2 = oe * oe;
    float lin = oe * fc_w[a];
    #pragma unroll
    for (int o = 1; o < 32; o <<= 1) lin += __shfl_xor(lin, o);
    float part = 0.f;
    #pragma unroll
    for (int j = 0; j < 10; j++) {
        float v = fm_V[a * 10 + j];
        float s1 = oe * v;
        float s2 = oe2 * v * v;
        #pragma unroll
        for (int o = 1; o < 32; o <<= 1) { s1 += __shfl_xor(s1, o); s2 += __shfl_xor(s2, o); }
        part += s1 * s1 - s2;
    }
    if (a == 0) {
        fm_lin[b] = lin + fc_b[0];
        parts[tid >> 5] = part;
    }
    __syncthreads();
    if (tid == 0) {
        float s = 0.f;
        #pragma unroll
        for (int i = 0; i < 8; ++i) s += parts[i];
        spart[blockIdx.x] = 0.5 * (double)s;
    }
}

// ---- K_predfinal: single block — S reduce, preds, rating loss, objective ----
__global__ __launch_bounds__(256) void k_predfinal(const float* __restrict__ label,
                                                   const float* __restrict__ fm_lin,
                                                   const double* __restrict__ spart,
                                                   const double* __restrict__ jpart,
                                                   const float* __restrict__ upart,
                                                   float* __restrict__ out) {
    __shared__ double dred[4];
    __shared__ float Ssh;
    __shared__ float ured[4];
    int tid = threadIdx.x;
    double sl = spart[tid] + spart[tid + 256];
    #pragma unroll
    for (int o = 32; o >= 1; o >>= 1) sl += __shfl_xor(sl, o);
    if ((tid & 63) == 0) dred[tid >> 6] = sl;
    __syncthreads();
    if (tid == 0) Ssh = (float)(dred[0] + dred[1] + dred[2] + dred[3]);
    __syncthreads();
    float S = Ssh;
    double racc = 0.0;
    #pragma unroll
    for (int i = 0; i < 16; ++i) {
        int b = tid + 256 * i;
        float pred = fm_lin[b] + S + AVG_RATING;
        float d = pred - label[b];
        float rl = d * d;
        out[OUT_PRED + b] = pred;
        out[OUT_RL + b] = rl;
        racc += (double)rl;
    }
    double jacc = 0.0;
    for (int i = tid; i < TAIL_GRID; i += 256) jacc += jpart[i];
    float u = (tid < 32) ? upart[tid] : 0.f;
    #pragma unroll
    for (int o = 32; o >= 1; o >>= 1) {
        racc += __shfl_xor(racc, o);
        jacc += __shfl_xor(jacc, o);
        u    += __shfl_xor(u, o);
    }
    __syncthreads();
    if ((tid & 63) == 0) dred[tid >> 6] = racc;
    __syncthreads();
    double rsum = dred[0] + dred[1] + dred[2] + dred[3];
    __syncthreads();
    if ((tid & 63) == 0) dred[tid >> 6] = jacc;
    __syncthreads();
    double jsum = dred[0] + dred[1] + dred[2] + dred[3];
    if ((tid & 63) == 0) ured[tid >> 6] = u;
    __syncthreads();
    if (tid == 0) {
        double U = (double)(ured[0] + ured[1] + ured[2] + ured[3]) / 1024.0;
        double J = jsum / (2.0 * R_CNT);
        double RL = rsum / (double)B_CNT;
        out[OUT_OBJ] = (float)(RL + U + J);
    }
}

extern "C" void kernel_launch(void* const* d_in, const int* in_sizes, int n_in,
                              void* d_out, int out_size, void* d_ws, size_t ws_size,
                              hipStream_t stream) {
    const float* e_w   = (const float*)d_in[0];
    const float* y_s   = (const float*)d_in[1];
    const float* z_n   = (const float*)d_in[2];
    const float* label = (const float*)d_in[3];
    const float* u_val = (const float*)d_in[4];
    const float* i_val = (const float*)d_in[5];
    const float* M_w   = (const float*)d_in[6];
    const float* W_w   = (const float*)d_in[8];
    const float* W_b   = (const float*)d_in[9];
    const float* T_w   = (const float*)d_in[10];
    const float* T_b   = (const float*)d_in[11];
    const float* fc_w  = (const float*)d_in[12];
    const float* fc_b  = (const float*)d_in[13];
    const float* fm_V  = (const float*)d_in[14];
    const int*   u_idx = (const int*)d_in[15];
    const int*   i_idx = (const int*)d_in[16];

    float* out = (float*)d_out;
    char* ws = (char*)d_ws;
    double* dbl   = (double*)(ws + WS_DBL);
    int* mode     = (int*)(ws + WS_MODE);
    float* fm_lin = (float*)(ws + WS_FMLIN);
    float* p_t    = (float*)(ws + WS_PT);
    float* V      = (float*)(ws + WS_V);   // becomes z_s in place
    double* jpart = (double*)(ws + WS_JPART);
    double* spart = (double*)(ws + WS_SPART);
    float* upart  = (float*)(ws + WS_UPART);

    k_pre<<<473, 256, 0, stream>>>(y_s, M_w, T_w, u_idx, V, upart, out, dbl, mode);
    k_flash<<<FLASH_GRID, 256, 0, stream>>>(e_w, V);
    k_tail<<<TAIL_GRID, 256, 0, stream>>>(V, z_n, W_w, W_b, T_w, T_b, p_t, out, jpart);
    k_scatter<<<(2 * NNZ_CNT * 32) / 256, 256, 0, stream>>>(u_idx, i_idx, u_val, i_val,
                                                            p_t, mode, out);
    k_fm<<<B_CNT / 8, 256, 0, stream>>>(out, fc_w, fc_b, fm_V, fm_lin, spart);
    k_predfinal<<<1, 256, 0, stream>>>(label, fm_lin, spart, jpart, upart, out);
}

// Round 11
// 323.452 us; speedup vs baseline: 2.2266x; 2.2266x over previous
//
#include <hip/hip_runtime.h>
#include <hip/hip_bf16.h>
#include <math.h>

#define R_CNT   20000
#define L_CNT   30
#define D_CNT   200
#define A_CNT   32
#define B_CNT   4096
#define NNZ_CNT 65536
#define AVG_RATING 3.8f

#define NW 1536           // k_zs: 1536 single-wave blocks (6/CU), 13-14 reviews each
#define TAIL_GRID 5000    // 4 reviews per block

// ---- d_out layout (floats) ----
#define OUT_OBJ  0
#define OUT_RL   1
#define OUT_AB   (1 + B_CNT)               // 4097
#define OUT_PRED (OUT_AB + 2*R_CNT)        // 44097
#define OUT_UA   (OUT_PRED + B_CNT)        // 48193
#define OUT_IA   (OUT_UA + B_CNT*A_CNT)    // 179265

// ---- ws layout (bytes) ----
#define WS_DBL    0         // double[4] (reserved)
#define WS_MODE   32        // int (1 => indices are int64 in memory)
#define WS_FMLIN  64        // float[4096]
#define WS_PT     16448     // float[R*32]
#define WS_V      2576448   // float[R*200]; k_zs overwrites row r with z_s
#define WS_JPART  18627648  // double[TAIL_GRID]
#define WS_SPART  18667648  // double[512]
#define WS_UPART  18671744  // float[32]

// Counted-vmcnt wait: chunk/V loads for the NEXT stage stay in flight.
#define WAITV16() do { asm volatile("s_waitcnt vmcnt(16)" ::: "memory"); \
                       __builtin_amdgcn_sched_barrier(0); } while (0)
#define SB0() __builtin_amdgcn_sched_barrier(0)

// Block-wide reduction of 4 channels across 256 threads (4 waves of 64).
__device__ __forceinline__ float4 blk_reduce4(float4 v, float4* scratch) {
    __syncthreads();
    #pragma unroll
    for (int o = 32; o >= 1; o >>= 1) {
        v.x += __shfl_xor(v.x, o);
        v.y += __shfl_xor(v.y, o);
        v.z += __shfl_xor(v.z, o);
        v.w += __shfl_xor(v.w, o);
    }
    int w = threadIdx.x >> 6;
    if ((threadIdx.x & 63) == 0) scratch[w] = v;
    __syncthreads();
    float4 t0 = scratch[0], t1 = scratch[1], t2 = scratch[2], t3 = scratch[3];
    return make_float4(t0.x + t1.x + t2.x + t3.x,
                       t0.y + t1.y + t2.y + t3.y,
                       t0.z + t1.z + t2.z + t3.z,
                       t0.w + t1.w + t2.w + t3.w);
}

// ---- K_pre: role-split fusion of {vgemm | uloss | init} ----
__global__ __launch_bounds__(256) void k_pre(const float* __restrict__ y_s,
                                             const float* __restrict__ M_w,
                                             const float* __restrict__ T_w,
                                             const int* __restrict__ u_idx,
                                             float* __restrict__ V,
                                             float* __restrict__ upart,
                                             float* __restrict__ out,
                                             double* __restrict__ dbl,
                                             int* __restrict__ mode) {
    __shared__ __align__(16) float sh[8224];
    const int tid = threadIdx.x;
    const int bid = blockIdx.x;

    if (bid < 313) {
        float* Msh = sh;             // [25][260]
        float* Ysh = sh + 6500;      // [25][68]
        int r0 = bid * 64;
        int dg = tid & 31, rg = tid >> 5;
        float acc[8][8];
        #pragma unroll
        for (int i = 0; i < 8; i++)
            #pragma unroll
            for (int j = 0; j < 8; j++) acc[i][j] = 0.f;
        for (int e0 = 0; e0 < D_CNT; e0 += 25) {
            __syncthreads();
            for (int idx = tid; idx < 25 * 256; idx += 256) {
                int ee = idx >> 8, d = idx & 255;
                Msh[ee * 260 + d] = (d < D_CNT) ? M_w[(e0 + ee) * D_CNT + d] : 0.f;
            }
            for (int idx = tid; idx < 25 * 64; idx += 256) {
                int rr = idx / 25, ee = idx - rr * 25;
                int row = r0 + rr;
                Ysh[ee * 68 + rr] = (row < R_CNT) ? y_s[row * D_CNT + e0 + ee] : 0.f;
            }
            __syncthreads();
            for (int ee = 0; ee < 25; ee++) {
                const float4 ya = *(const float4*)&Ysh[ee * 68 + rg * 8];
                const float4 yb = *(const float4*)&Ysh[ee * 68 + rg * 8 + 4];
                const float4 ma = *(const float4*)&Msh[ee * 260 + dg * 8];
                const float4 mb = *(const float4*)&Msh[ee * 260 + dg * 8 + 4];
                float ys[8] = {ya.x, ya.y, ya.z, ya.w, yb.x, yb.y, yb.z, yb.w};
                float ms[8] = {ma.x, ma.y, ma.z, ma.w, mb.x, mb.y, mb.z, mb.w};
                #pragma unroll
                for (int i = 0; i < 8; i++)
                    #pragma unroll
                    for (int j = 0; j < 8; j++)
                        acc[i][j] = fmaf(ys[i], ms[j], acc[i][j]);
            }
        }
        if (dg < 25) {
            #pragma unroll
            for (int i = 0; i < 8; i++) {
                int row = r0 + rg * 8 + i;
                if (row < R_CNT) {
                    *(float4*)&V[row * D_CNT + dg * 8]     = make_float4(acc[i][0], acc[i][1], acc[i][2], acc[i][3]);
                    *(float4*)&V[row * D_CNT + dg * 8 + 4] = make_float4(acc[i][4], acc[i][5], acc[i][6], acc[i][7]);
                }
            }
        }
    } else if (bid < 345) {
        float* Tsh = sh;                         // 6400 floats
        float* tn  = sh + 6400;                  // 32
        float4* red4 = (float4*)(sh + 6448);     // 16 floats
        for (int idx = tid; idx < 1600; idx += 256)
            ((float4*)Tsh)[idx] = ((const float4*)T_w)[idx];
        __syncthreads();
        int a = tid >> 3, k = tid & 7;
        float p = 0.f;
        #pragma unroll
        for (int j = 0; j < 25; ++j) { float t = Tsh[(k + 8*j)*32 + a]; p = fmaf(t, t, p); }
        p += __shfl_xor(p, 1); p += __shfl_xor(p, 2); p += __shfl_xor(p, 4);
        if (k == 0) tn[a] = fmaxf(sqrtf(p), 1e-12f);
        __syncthreads();
        const int i = bid - 313;
        float s = 0.f;
        #pragma unroll
        for (int j = 0; j < 25; ++j)
            s = fmaf(Tsh[(k + 8*j)*32 + i], Tsh[(k + 8*j)*32 + a], s);
        s += __shfl_xor(s, 1); s += __shfl_xor(s, 2); s += __shfl_xor(s, 4);
        float part = 0.f;
        if (k == 0) {
            float g = s / (tn[i] * tn[a]);
            float diff = g - ((i == a) ? 1.f : 0.f);
            part = diff * diff;
        }
        float4 tot = blk_reduce4(make_float4(part, 0.f, 0.f, 0.f), red4);
        if (tid == 0) upart[i] = tot.x;
    } else {
        int base = (bid - 345) * 2048;
        #pragma unroll
        for (int j = 0; j < 8; ++j)
            out[OUT_UA + base + j * 256 + tid] = 0.f;
        if (bid == 345 && tid == 0) {
            dbl[0] = 0.0; dbl[1] = 0.0; dbl[2] = 0.0;
            int m = 1;
            for (int i = 1; i < 256; i += 2) if (u_idx[i] != 0) { m = 0; break; }
            *mode = m;
        }
    }
}

// ---- k_zs staging: gload_lds, fixed instruction counts (12 and 4) ----
__device__ __forceinline__ void stage_chunk(const float* src, float* lds,
                                            int lane, const float* ew_last4) {
    #pragma unroll
    for (int i = 0; i < 12; ++i) {
        const float* p = src + i * 256 + lane * 4;
        if (p > ew_last4) p = ew_last4;   // clamp tail (pad LDS slots get dup data)
        __builtin_amdgcn_global_load_lds(
            (const __attribute__((address_space(1))) unsigned int*)p,
            (__attribute__((address_space(3))) unsigned int*)(lds + i * 256),
            16, 0, 0);
    }
}
__device__ __forceinline__ void stage_v(const float* vsrc, float* lds, int lane) {
    #pragma unroll
    for (int i = 0; i < 4; ++i)
        __builtin_amdgcn_global_load_lds(
            (const __attribute__((address_space(1))) unsigned int*)(vsrc + i * 64 + lane),
            (__attribute__((address_space(3))) unsigned int*)(lds + i * 64),
            4, 0, 0);
}

// One half-review chunk (15 rows): dx -> online-softmax merge -> z accum.
// Wave-synchronous: no barriers, LDS broadcast via dxs scratch.
__device__ __forceinline__ void chunk_pass(const float* __restrict__ eb,
                                           const float* __restrict__ vb,
                                           float* __restrict__ dxs,
                                           int lane, float& m, float& s,
                                           float4& zacc) {
    int l = lane >> 2, k = lane & 3;
    float p = 0.f;
    if (l < 15) {
        const float4* er = (const float4*)(eb + l * 200);
        const float4* vr = (const float4*)vb;
        #pragma unroll
        for (int t = 0; t < 13; ++t) {
            int idx = k + 4 * t;
            if (idx < 50) {
                float4 e = er[idx], v = vr[idx];
                p += e.x * v.x + e.y * v.y + e.z * v.z + e.w * v.w;
            }
        }
    }
    p += __shfl_xor(p, 1);
    p += __shfl_xor(p, 2);
    if (l < 15 && k == 0) dxs[l] = p;
    float4 d0 = ((const float4*)dxs)[0];
    float4 d1 = ((const float4*)dxs)[1];
    float4 d2 = ((const float4*)dxs)[2];
    float4 d3 = ((const float4*)dxs)[3];
    float dx[15] = {d0.x, d0.y, d0.z, d0.w, d1.x, d1.y, d1.z, d1.w,
                    d2.x, d2.y, d2.z, d2.w, d3.x, d3.y, d3.z};
    float cm = dx[0];
    #pragma unroll
    for (int q = 1; q < 15; ++q) cm = fmaxf(cm, dx[q]);
    float mn = fmaxf(m, cm);
    float sc = __expf(m - mn);
    float w[15];
    float ss = 0.f;
    #pragma unroll
    for (int q = 0; q < 15; ++q) { w[q] = __expf(dx[q] - mn); ss += w[q]; }
    s = s * sc + ss;
    zacc.x *= sc; zacc.y *= sc; zacc.z *= sc; zacc.w *= sc;
    if (lane < 50) {
        #pragma unroll
        for (int q = 0; q < 15; ++q) {
            float4 e = ((const float4*)(eb + q * 200))[lane];
            zacc.x = fmaf(w[q], e.x, zacc.x);
            zacc.y = fmaf(w[q], e.y, zacc.y);
            zacc.z = fmaf(w[q], e.z, zacc.z);
            zacc.w = fmaf(w[q], e.w, zacc.w);
        }
    }
    m = mn;
}

// ---- K_zs: single-wave blocks, zero barriers, chunked double-buffered
// gload_lds pipeline with uniform vmcnt(16) waits. z_s overwrites V[r]. ----
__global__ __launch_bounds__(64) void k_zs(const float* __restrict__ e_w,
                                           float* __restrict__ V) {
    __shared__ __align__(16) float bufE[2][3072];   // 2 x 12.0KB (+pad)
    __shared__ __align__(16) float bufV[2][256];    // v row + dxs scratch @208
    const int lane = threadIdx.x;
    const float* ew_last4 = e_w + (size_t)R_CNT * 6000 - 4;

    int rev = blockIdx.x;
    // prologue: v(rev) [4] + chunkA(rev) [12]  -> 16 outstanding
    stage_v(V + (size_t)rev * 200, bufV[0], lane);
    stage_chunk(e_w + (size_t)rev * 6000, bufE[0], lane, ew_last4);
    int pv = 0;
    for (;;) {
        float m = -3.0e38f, s = 0.f;
        float4 zacc = make_float4(0.f, 0.f, 0.f, 0.f);
        SB0();
        stage_chunk(e_w + (size_t)rev * 6000 + 3000, bufE[1], lane, ew_last4);  // +12
        int rnext = rev + NW;
        bool last = (rnext >= R_CNT);
        int rc = last ? rev : rnext;
        stage_v(V + (size_t)rc * 200, bufV[pv ^ 1], lane);                      // +4
        WAITV16();   // chunkA + v(rev) landed; 16 newest stay in flight
        chunk_pass(bufE[0], bufV[pv], bufV[pv] + 208, lane, m, s, zacc);
        SB0();
        stage_chunk(e_w + (size_t)rc * 6000, bufE[0], lane, ew_last4);          // +12
        WAITV16();   // chunkB landed; v(next)+chunkA(next) stay in flight
        chunk_pass(bufE[1], bufV[pv], bufV[pv] + 208, lane, m, s, zacc);
        float inv = 1.f / s;
        if (lane < 50) {
            float4 z = make_float4(zacc.x * inv, zacc.y * inv,
                                   zacc.z * inv, zacc.w * inv);
            ((float4*)(V + (size_t)rev * 200))[lane] = z;                       // +1
        }
        if (last) break;
        rev = rnext;
        pv ^= 1;
    }
}

// ---- K_tail: p_t + r_s + cosine hinge losses, 4 reviews per block ----
__global__ __launch_bounds__(256) void k_tail(const float* __restrict__ zs,
                                              const float* __restrict__ z_n,
                                              const float* __restrict__ W_w,
                                              const float* __restrict__ W_b,
                                              const float* __restrict__ T_w,
                                              const float* __restrict__ T_b,
                                              float* __restrict__ p_t,
                                              float* __restrict__ out,
                                              double* __restrict__ jpart) {
    __shared__ __align__(16) float zsh[4 * D_CNT];
    __shared__ float pts[4 * 32];
    __shared__ float4 red[8];
    const int tid = threadIdx.x;
    const int w = tid >> 6;
    const int r0 = blockIdx.x * 4;

    for (int i = tid; i < 200; i += 256)
        ((float4*)zsh)[i] = ((const float4*)(zs + (size_t)r0 * D_CNT))[i];

    float zn[8];
    #pragma unroll
    for (int q = 0; q < 8; ++q) zn[q] = 0.f;
    if (tid < D_CNT) {
        #pragma unroll
        for (int q = 0; q < 4; ++q) {
            zn[2*q]   = z_n[(size_t)(2*(r0+q))     * D_CNT + tid];
            zn[2*q+1] = z_n[(size_t)(2*(r0+q) + 1) * D_CNT + tid];
        }
    }
    __syncthreads();

    {
        int a = tid >> 3, k = tid & 7;
        float a0 = 0.f, a1 = 0.f, a2 = 0.f, a3 = 0.f;
        #pragma unroll
        for (int j = 0; j < 25; ++j) {
            float wv = W_w[a * D_CNT + k + 8 * j];
            a0 = fmaf(zsh[0*D_CNT + k + 8*j], wv, a0);
            a1 = fmaf(zsh[1*D_CNT + k + 8*j], wv, a1);
            a2 = fmaf(zsh[2*D_CNT + k + 8*j], wv, a2);
            a3 = fmaf(zsh[3*D_CNT + k + 8*j], wv, a3);
        }
        #pragma unroll
        for (int o = 1; o < 8; o <<= 1) {
            a0 += __shfl_xor(a0, o); a1 += __shfl_xor(a1, o);
            a2 += __shfl_xor(a2, o); a3 += __shfl_xor(a3, o);
        }
        if (k == 0) {
            float wbv = W_b[a];
            float p0 = a0 + wbv, p1 = a1 + wbv, p2 = a2 + wbv, p3 = a3 + wbv;
            pts[0*32+a] = p0; pts[1*32+a] = p1; pts[2*32+a] = p2; pts[3*32+a] = p3;
            p_t[(size_t)(r0+0) * 32 + a] = p0;
            p_t[(size_t)(r0+1) * 32 + a] = p1;
            p_t[(size_t)(r0+2) * 32 + a] = p2;
            p_t[(size_t)(r0+3) * 32 + a] = p3;
        }
    }
    __syncthreads();

    float rv[4] = {0.f, 0.f, 0.f, 0.f};
    float zv[4] = {0.f, 0.f, 0.f, 0.f};
    if (tid < D_CNT) {
        float tbv = T_b[tid];
        rv[0] = tbv; rv[1] = tbv; rv[2] = tbv; rv[3] = tbv;
        const float4* tw = (const float4*)(T_w + tid * 32);
        #pragma unroll
        for (int u = 0; u < 8; ++u) {
            float4 t = tw[u];
            #pragma unroll
            for (int q = 0; q < 4; ++q) {
                rv[q] = fmaf(t.x, pts[q*32 + 4*u + 0], rv[q]);
                rv[q] = fmaf(t.y, pts[q*32 + 4*u + 1], rv[q]);
                rv[q] = fmaf(t.z, pts[q*32 + 4*u + 2], rv[q]);
                rv[q] = fmaf(t.w, pts[q*32 + 4*u + 3], rv[q]);
            }
        }
        #pragma unroll
        for (int q = 0; q < 4; ++q) zv[q] = zsh[q * D_CNT + tid];
    }

    double jloc = 0.0;
    #pragma unroll
    for (int q = 0; q < 4; ++q) {
        float4 Av = make_float4(rv[q]*rv[q], rv[q]*zv[q], zv[q]*zv[q], zn[2*q]*zn[2*q]);
        float4 Bv = make_float4(zn[2*q]*rv[q], zn[2*q+1]*zn[2*q+1], zn[2*q+1]*rv[q], 0.f);
        #pragma unroll
        for (int o = 32; o >= 1; o >>= 1) {
            Av.x += __shfl_xor(Av.x, o); Av.y += __shfl_xor(Av.y, o);
            Av.z += __shfl_xor(Av.z, o); Av.w += __shfl_xor(Av.w, o);
            Bv.x += __shfl_xor(Bv.x, o); Bv.y += __shfl_xor(Bv.y, o);
            Bv.z += __shfl_xor(Bv.z, o);
        }
        if ((tid & 63) == 0) { red[2*w] = Av; red[2*w+1] = Bv; }
        __syncthreads();
        if (tid == 0) {
            float rr = 0.f, rz = 0.f, zz = 0.f, n00 = 0.f, n0r = 0.f, n11 = 0.f, n1r = 0.f;
            #pragma unroll
            for (int i = 0; i < 4; ++i) {
                float4 a = red[2*i], b = red[2*i+1];
                rr += a.x; rz += a.y; zz += a.z; n00 += a.w;
                n0r += b.x; n11 += b.y; n1r += b.z;
            }
            float nr = fmaxf(sqrtf(rr), 1e-12f);
            float nz = fmaxf(sqrtf(zz), 1e-12f);
            float c1  = rz  / (nr * nz);
            float c20 = n0r / (fmaxf(sqrtf(n00), 1e-12f) * nr);
            float c21 = n1r / (fmaxf(sqrtf(n11), 1e-12f) * nr);
            float l0 = fmaxf(0.f, 1.f - (c1 - c20));
            float l1 = fmaxf(0.f, 1.f - (c1 - c21));
            out[OUT_AB + 2 * (r0 + q)]     = l0;
            out[OUT_AB + 2 * (r0 + q) + 1] = l1;
            jloc += (double)l0 + (double)l1;
        }
        __syncthreads();
    }
    if (tid == 0) jpart[blockIdx.x] = jloc;
}

// ---- K_scatter: user/item aspect segment sums via atomics ----
__global__ __launch_bounds__(256) void k_scatter(const int* __restrict__ u_idx,
                                                 const int* __restrict__ i_idx,
                                                 const float* __restrict__ u_val,
                                                 const float* __restrict__ i_val,
                                                 const float* __restrict__ p_t,
                                                 const int* __restrict__ mode,
                                                 float* __restrict__ out) {
    long long gid = (long long)blockIdx.x * 256 + threadIdx.x;
    const long long HALF = (long long)NNZ_CNT * 32;
    int is_item = gid >= HALF;
    long long rem = gid - (is_item ? HALF : 0);
    int k = (int)(rem >> 5), a = (int)(rem & 31);
    const int* idx = is_item ? i_idx : u_idx;
    const float* val = is_item ? i_val : u_val;
    int m64 = *mode;
    int row, col;
    if (m64) { row = idx[2 * k]; col = idx[2 * (NNZ_CNT + k)]; }
    else     { row = idx[k];     col = idx[NNZ_CNT + k]; }
    float v = p_t[col * 32 + a] * val[k];
    float* base = out + (is_item ? OUT_IA : OUT_UA);
    atomicAdd(&base[row * 32 + a], v);
}

// ---- K_fm: FM per-b terms; per-block partial of the global scalar S ----
__global__ __launch_bounds__(256) void k_fm(const float* __restrict__ out,
                                            const float* __restrict__ fc_w,
                                            const float* __restrict__ fc_b,
                                            const float* __restrict__ fm_V,
                                            float* __restrict__ fm_lin,
                                            double* __restrict__ spart) {
    __shared__ float parts[8];
    int tid = threadIdx.x;
    int a = tid & 31;
    int b = blockIdx.x * 8 + (tid >> 5);
    float ua = out[OUT_UA + b * 32 + a];
    float ia = out[OUT_IA + b * 32 + a];
    float oe = ua * ia;
    float oe2 = oe * oe;
    float lin = oe * fc_w[a];
    #pragma unroll
    for (int o = 1; o < 32; o <<= 1) lin += __shfl_xor(lin, o);
    float part = 0.f;
    #pragma unroll
    for (int j = 0; j < 10; j++) {
        float v = fm_V[a * 10 + j];
        float s1 = oe * v;
        float s2 = oe2 * v * v;
        #pragma unroll
        for (int o = 1; o < 32; o <<= 1) { s1 += __shfl_xor(s1, o); s2 += __shfl_xor(s2, o); }
        part += s1 * s1 - s2;
    }
    if (a == 0) {
        fm_lin[b] = lin + fc_b[0];
        parts[tid >> 5] = part;
    }
    __syncthreads();
    if (tid == 0) {
        float s = 0.f;
        #pragma unroll
        for (int i = 0; i < 8; ++i) s += parts[i];
        spart[blockIdx.x] = 0.5 * (double)s;
    }
}

// ---- K_predfinal: single block — S reduce, preds, rating loss, objective ----
__global__ __launch_bounds__(256) void k_predfinal(const float* __restrict__ label,
                                                   const float* __restrict__ fm_lin,
                                                   const double* __restrict__ spart,
                                                   const double* __restrict__ jpart,
                                                   const float* __restrict__ upart,
                                                   float* __restrict__ out) {
    __shared__ double dred[4];
    __shared__ float Ssh;
    __shared__ float ured[4];
    int tid = threadIdx.x;
    double sl = spart[tid] + spart[tid + 256];
    #pragma unroll
    for (int o = 32; o >= 1; o >>= 1) sl += __shfl_xor(sl, o);
    if ((tid & 63) == 0) dred[tid >> 6] = sl;
    __syncthreads();
    if (tid == 0) Ssh = (float)(dred[0] + dred[1] + dred[2] + dred[3]);
    __syncthreads();
    float S = Ssh;
    double racc = 0.0;
    #pragma unroll
    for (int i = 0; i < 16; ++i) {
        int b = tid + 256 * i;
        float pred = fm_lin[b] + S + AVG_RATING;
        float d = pred - label[b];
        float rl = d * d;
        out[OUT_PRED + b] = pred;
        out[OUT_RL + b] = rl;
        racc += (double)rl;
    }
    double jacc = 0.0;
    for (int i = tid; i < TAIL_GRID; i += 256) jacc += jpart[i];
    float u = (tid < 32) ? upart[tid] : 0.f;
    #pragma unroll
    for (int o = 32; o >= 1; o >>= 1) {
        racc += __shfl_xor(racc, o);
        jacc += __shfl_xor(jacc, o);
        u    += __shfl_xor(u, o);
    }
    __syncthreads();
    if ((tid & 63) == 0) dred[tid >> 6] = racc;
    __syncthreads();
    double rsum = dred[0] + dred[1] + dred[2] + dred[3];
    __syncthreads();
    if ((tid & 63) == 0) dred[tid >> 6] = jacc;
    __syncthreads();
    double jsum = dred[0] + dred[1] + dred[2] + dred[3];
    if ((tid & 63) == 0) ured[tid >> 6] = u;
    __syncthreads();
    if (tid == 0) {
        double U = (double)(ured[0] + ured[1] + ured[2] + ured[3]) / 1024.0;
        double J = jsum / (2.0 * R_CNT);
        double RL = rsum / (double)B_CNT;
        out[OUT_OBJ] = (float)(RL + U + J);
    }
}

extern "C" void kernel_launch(void* const* d_in, const int* in_sizes, int n_in,
                              void* d_out, int out_size, void* d_ws, size_t ws_size,
                              hipStream_t stream) {
    const float* e_w   = (const float*)d_in[0];
    const float* y_s   = (const float*)d_in[1];
    const float* z_n   = (const float*)d_in[2];
    const float* label = (const float*)d_in[3];
    const float* u_val = (const float*)d_in[4];
    const float* i_val = (const float*)d_in[5];
    const float* M_w   = (const float*)d_in[6];
    const float* W_w   = (const float*)d_in[8];
    const float* W_b   = (const float*)d_in[9];
    const float* T_w   = (const float*)d_in[10];
    const float* T_b   = (const float*)d_in[11];
    const float* fc_w  = (const float*)d_in[12];
    const float* fc_b  = (const float*)d_in[13];
    const float* fm_V  = (const float*)d_in[14];
    const int*   u_idx = (const int*)d_in[15];
    const int*   i_idx = (const int*)d_in[16];

    float* out = (float*)d_out;
    char* ws = (char*)d_ws;
    double* dbl   = (double*)(ws + WS_DBL);
    int* mode     = (int*)(ws + WS_MODE);
    float* fm_lin = (float*)(ws + WS_FMLIN);
    float* p_t    = (float*)(ws + WS_PT);
    float* V      = (float*)(ws + WS_V);   // becomes z_s in place
    double* jpart = (double*)(ws + WS_JPART);
    double* spart = (double*)(ws + WS_SPART);
    float* upart  = (float*)(ws + WS_UPART);

    k_pre<<<473, 256, 0, stream>>>(y_s, M_w, T_w, u_idx, V, upart, out, dbl, mode);
    k_zs<<<NW, 64, 0, stream>>>(e_w, V);
    k_tail<<<TAIL_GRID, 256, 0, stream>>>(V, z_n, W_w, W_b, T_w, T_b, p_t, out, jpart);
    k_scatter<<<(2 * NNZ_CNT * 32) / 256, 256, 0, stream>>>(u_idx, i_idx, u_val, i_val,
                                                            p_t, mode, out);
    k_fm<<<B_CNT / 8, 256, 0, stream>>>(out, fc_w, fc_b, fm_V, fm_lin, spart);
    k_predfinal<<<1, 256, 0, stream>>>(label, fm_lin, spart, jpart, upart, out);
}